// Round 1
// baseline (351.548 us; speedup 1.0000x reference)
//
#include <hip/hip_runtime.h>
#include <hip/hip_bf16.h>

#define SEQ 1024
#define NH 8
#define HD 64           // head dim
#define HID 512
#define BATCH 32

typedef _Float16 f16;
typedef f16 f16x8 __attribute__((ext_vector_type(8)));
typedef float f32x4 __attribute__((ext_vector_type(4)));

// ---------------------------------------------------------------------------
// Kernel 1: transpose weights to f16, k-contiguous (B-operand layout)
//   wTq[j][e] = w_qkv[e][j]   (1536 x 64)
//   wTp[n][k] = w_proj[k][n]  (64 x 512)
// ---------------------------------------------------------------------------
__global__ __launch_bounds__(256) void transpose_w(const float* __restrict__ wq,
                                                   const float* __restrict__ wp,
                                                   f16* __restrict__ wTq,
                                                   f16* __restrict__ wTp) {
    int flat = blockIdx.x * 256 + threadIdx.x;   // 0 .. 131071
    if (flat < 64 * 1536) {
        int e = flat / 1536, j = flat % 1536;
        wTq[(size_t)j * 64 + e] = (f16)wq[flat];
    } else {
        int f2 = flat - 64 * 1536;               // 0 .. 32767, w_proj is (512,64)
        int k = f2 / 64, n = f2 % 64;
        wTp[(size_t)n * 512 + k] = (f16)wp[f2];
    }
}

// ---------------------------------------------------------------------------
// Kernel 2: QKV projection with MFMA.
// Block: 256 thr, handles 64 rows (n) for one bh. Writes:
//   Qb[bh][n][d], Kb[bh][n][d]  (row-major, d contiguous)
//   Vtb[bh][d][n]               (transposed: n contiguous)
// ---------------------------------------------------------------------------
__global__ __launch_bounds__(256) void qkv_kernel(const float* __restrict__ x,
                                                  const f16* __restrict__ wTq,
                                                  const float* __restrict__ b_qkv,
                                                  f16* __restrict__ Qb,
                                                  f16* __restrict__ Kb,
                                                  f16* __restrict__ Vtb) {
    __shared__ __align__(16) f16 x_lds[64][72];
    __shared__ __align__(16) f16 w_lds[192][72];

    const int n0   = blockIdx.x * 64;
    const int bh   = blockIdx.y;
    const int b    = bh >> 3, h = bh & 7;
    const int tid  = threadIdx.x;
    const int wave = tid >> 6, lane = tid & 63;
    const int quad = lane >> 4, l16 = lane & 15;

    // stage x tile (64x64 fp32 -> f16)
    for (int p = 0; p < 2; p++) {
        int t = tid + p * 256;
        int row = t >> 3, col = (t & 7) * 8;
        const float* src = x + ((size_t)(b * SEQ + n0 + row)) * 64 + col;
        float4 a0 = *(const float4*)src;
        float4 a1 = *(const float4*)(src + 4);
        f16x8 v = {(f16)a0.x, (f16)a0.y, (f16)a0.z, (f16)a0.w,
                   (f16)a1.x, (f16)a1.y, (f16)a1.z, (f16)a1.w};
        *(f16x8*)(&x_lds[row][col]) = v;
    }
    // stage wT slice for this head: rows h*192 .. h*192+191, each 64 f16
    for (int p = 0; p < 6; p++) {
        int row = p * 32 + (tid >> 3), col = (tid & 7) * 8;
        *(f16x8*)(&w_lds[row][col]) =
            *(const f16x8*)(wTq + (size_t)(h * 192 + row) * 64 + col);
    }
    __syncthreads();

    // wave -> m-tile (16 rows); 12 n-tiles of 16 over the 192 outputs
    f16x8 af[2];
    af[0] = *(const f16x8*)(&x_lds[wave * 16 + l16][quad * 8]);
    af[1] = *(const f16x8*)(&x_lds[wave * 16 + l16][quad * 8 + 32]);

    f32x4 acc[12];
    f32x4 z = {0.f, 0.f, 0.f, 0.f};
    for (int jt = 0; jt < 12; jt++) acc[jt] = z;

    for (int jt = 0; jt < 12; jt++)
        for (int ss = 0; ss < 2; ss++) {
            f16x8 bf = *(const f16x8*)(&w_lds[jt * 16 + l16][quad * 8 + ss * 32]);
            acc[jt] = __builtin_amdgcn_mfma_f32_16x16x32_f16(af[ss], bf, acc[jt], 0, 0, 0);
        }

    // epilogue: split (h,d,c) layout, scatter to Q/K/Vt
    for (int jt = 0; jt < 12; jt++) {
        int jl = jt * 16 + l16;            // 0..191
        float bias = b_qkv[h * 192 + jl];
        int d = jl / 3, c = jl - 3 * d;
        for (int r = 0; r < 4; r++) {
            int n = n0 + wave * 16 + quad * 4 + r;
            f16 val = (f16)(acc[jt][r] + bias);
            if (c == 0)      Qb[((size_t)bh * SEQ + n) * HD + d] = val;
            else if (c == 1) Kb[((size_t)bh * SEQ + n) * HD + d] = val;
            else             Vtb[((size_t)bh * HD + d) * SEQ + n] = val;
        }
    }
}

// ---------------------------------------------------------------------------
// Kernel 3: fused flash attention. Block: 256 thr = 4 waves, 64 q-rows
// per block (16 per wave). K-tile = 64 keys. Online softmax.
// Epilogue applies the reference's post-softmax /8: O = (P/(8*l)) @ V.
// Output: attn[b][n][h*64+d]  (f16)
// ---------------------------------------------------------------------------
__global__ __launch_bounds__(256) void flash_kernel(const f16* __restrict__ Qb,
                                                    const f16* __restrict__ Kb,
                                                    const f16* __restrict__ Vtb,
                                                    f16* __restrict__ attn) {
    __shared__ __align__(16) f16 k_lds[64][72];
    __shared__ __align__(16) f16 vt_lds[64][72];
    __shared__ __align__(16) f16 p_lds[4][16][72];

    const int qt   = blockIdx.x;          // 0..15
    const int h    = blockIdx.y;          // 0..7
    const int b    = blockIdx.z;          // 0..31
    const int bh   = b * NH + h;
    const int tid  = threadIdx.x;
    const int wave = tid >> 6, lane = tid & 63;
    const int quad = lane >> 4, l16 = lane & 15;

    // Q fragments (held in registers for whole kernel)
    const f16* qbase = Qb + ((size_t)bh * SEQ + qt * 64 + wave * 16) * HD;
    f16x8 qfrag[2];
    qfrag[0] = *(const f16x8*)(qbase + (size_t)l16 * HD + quad * 8);
    qfrag[1] = *(const f16x8*)(qbase + (size_t)l16 * HD + quad * 8 + 32);

    float m_st[4], l_st[4];
    f32x4 o_acc[4];
    f32x4 z = {0.f, 0.f, 0.f, 0.f};
    for (int r = 0; r < 4; r++) { m_st[r] = -INFINITY; l_st[r] = 0.f; }
    for (int nt = 0; nt < 4; nt++) o_acc[nt] = z;

    const f16* kg0 = Kb  + (size_t)bh * SEQ * HD;
    const f16* vg0 = Vtb + (size_t)bh * HD * SEQ;

    for (int kt = 0; kt < SEQ / 64; kt++) {
        __syncthreads();
        // stage K tile (rows = local key, 64 f16 each) and Vt tile (rows = d)
        const f16* kg = kg0 + (size_t)(kt * 64) * HD;
        const f16* vg = vg0 + kt * 64;
        for (int p = 0; p < 2; p++) {
            int t = tid + p * 256;
            int row = t >> 3, col = (t & 7) * 8;
            *(f16x8*)(&k_lds[row][col])  = *(const f16x8*)(kg + (size_t)row * HD + col);
            *(f16x8*)(&vt_lds[row][col]) = *(const f16x8*)(vg + (size_t)row * SEQ + col);
        }
        __syncthreads();

        // S = Q @ K^T   (16 x 64 per wave, 4 col-tiles)
        f32x4 s[4];
        for (int ct = 0; ct < 4; ct++) {
            f32x4 acc = z;
            for (int ss = 0; ss < 2; ss++) {
                f16x8 bf = *(const f16x8*)(&k_lds[ct * 16 + l16][quad * 8 + ss * 32]);
                acc = __builtin_amdgcn_mfma_f32_16x16x32_f16(qfrag[ss], bf, acc, 0, 0, 0);
            }
            s[ct] = acc;
        }

        // online softmax per q-row (row = quad*4+r, owned by the 16 lanes of quad)
        for (int r = 0; r < 4; r++) {
            float mx = fmaxf(fmaxf(s[0][r], s[1][r]), fmaxf(s[2][r], s[3][r]));
            for (int off = 1; off < 16; off <<= 1)
                mx = fmaxf(mx, __shfl_xor(mx, off, 64));
            float m_new = fmaxf(m_st[r], mx);
            float alpha = __expf(m_st[r] - m_new);
            float rs = 0.f;
            for (int ct = 0; ct < 4; ct++) {
                float p = __expf(s[ct][r] - m_new);
                s[ct][r] = p;
                rs += p;
            }
            for (int off = 1; off < 16; off <<= 1)
                rs += __shfl_xor(rs, off, 64);
            l_st[r] = l_st[r] * alpha + rs;
            m_st[r] = m_new;
            for (int nt = 0; nt < 4; nt++) o_acc[nt][r] *= alpha;
        }

        // P -> LDS (C-layout -> A-layout round trip; per-wave region)
        for (int ct = 0; ct < 4; ct++)
            for (int r = 0; r < 4; r++)
                p_lds[wave][quad * 4 + r][ct * 16 + l16] = (f16)s[ct][r];
        __asm__ volatile("s_waitcnt lgkmcnt(0)" ::: "memory");

        // O += P @ V
        for (int ss = 0; ss < 2; ss++) {
            f16x8 af = *(const f16x8*)(&p_lds[wave][l16][quad * 8 + ss * 32]);
            for (int nt = 0; nt < 4; nt++) {
                f16x8 bf = *(const f16x8*)(&vt_lds[nt * 16 + l16][quad * 8 + ss * 32]);
                o_acc[nt] = __builtin_amdgcn_mfma_f32_16x16x32_f16(af, bf, o_acc[nt], 0, 0, 0);
            }
        }
    }

    // epilogue: O / (8 * l)  -> attn[b][n][h*64+d]
    f16* ob = attn + ((size_t)(b * SEQ) + qt * 64 + wave * 16) * HID + h * HD;
    for (int r = 0; r < 4; r++) {
        float sc = 1.0f / (8.0f * l_st[r]);
        for (int nt = 0; nt < 4; nt++)
            ob[(size_t)(quad * 4 + r) * HID + nt * 16 + l16] = (f16)(o_acc[nt][r] * sc);
    }
}

// ---------------------------------------------------------------------------
// Kernel 4: output projection. attn (32768 x 512) @ w_proj (512 x 64) + b.
// Block: 256 thr, 64 rows; loop 8 k-tiles of 64. fp32 output.
// ---------------------------------------------------------------------------
__global__ __launch_bounds__(256) void proj_kernel(const f16* __restrict__ attn,
                                                   const f16* __restrict__ wTp,
                                                   const float* __restrict__ b_proj,
                                                   float* __restrict__ out) {
    __shared__ __align__(16) f16 a_lds[64][72];
    __shared__ __align__(16) f16 w_lds[64][72];

    const int blk  = blockIdx.x;          // row tile
    const int tid  = threadIdx.x;
    const int wave = tid >> 6, lane = tid & 63;
    const int quad = lane >> 4, l16 = lane & 15;

    f32x4 acc[4];
    f32x4 z = {0.f, 0.f, 0.f, 0.f};
    for (int ct = 0; ct < 4; ct++) acc[ct] = z;

    for (int kt = 0; kt < 8; kt++) {
        __syncthreads();
        for (int p = 0; p < 2; p++) {
            int t = tid + p * 256;
            int row = t >> 3, col = (t & 7) * 8;
            *(f16x8*)(&a_lds[row][col]) =
                *(const f16x8*)(attn + ((size_t)(blk * 64 + row)) * HID + kt * 64 + col);
            *(f16x8*)(&w_lds[row][col]) =
                *(const f16x8*)(wTp + (size_t)row * HID + kt * 64 + col);
        }
        __syncthreads();
        for (int ss = 0; ss < 2; ss++) {
            f16x8 af = *(const f16x8*)(&a_lds[wave * 16 + l16][quad * 8 + ss * 32]);
            for (int ct = 0; ct < 4; ct++) {
                f16x8 bf = *(const f16x8*)(&w_lds[ct * 16 + l16][quad * 8 + ss * 32]);
                acc[ct] = __builtin_amdgcn_mfma_f32_16x16x32_f16(af, bf, acc[ct], 0, 0, 0);
            }
        }
    }

    for (int ct = 0; ct < 4; ct++) {
        float bias = b_proj[ct * 16 + l16];
        for (int r = 0; r < 4; r++) {
            int row = blk * 64 + wave * 16 + quad * 4 + r;
            out[(size_t)row * HD + ct * 16 + l16] = acc[ct][r] + bias;
        }
    }
}

// ---------------------------------------------------------------------------
extern "C" void kernel_launch(void* const* d_in, const int* in_sizes, int n_in,
                              void* d_out, int out_size, void* d_ws, size_t ws_size,
                              hipStream_t stream) {
    (void)in_sizes; (void)n_in; (void)out_size; (void)ws_size;
    const float* x      = (const float*)d_in[0];
    const float* w_qkv  = (const float*)d_in[1];
    const float* b_qkv  = (const float*)d_in[2];
    const float* w_proj = (const float*)d_in[3];
    const float* b_proj = (const float*)d_in[4];
    float* out = (float*)d_out;

    char* ws = (char*)d_ws;
    const size_t QKV_EL = (size_t)BATCH * NH * SEQ * HD;   // 16,777,216
    f16* wTq  = (f16*)(ws);                                 // 1536x64
    f16* wTp  = (f16*)(ws + 196608);                        // 64x512
    f16* Qb   = (f16*)(ws + 262144);
    f16* Kb   = (f16*)(ws + 262144 + 2 * QKV_EL);
    f16* Vtb  = (f16*)(ws + 262144 + 4 * QKV_EL);
    f16* attn = (f16*)(ws + 262144 + 6 * QKV_EL);

    transpose_w<<<512, 256, 0, stream>>>(w_qkv, w_proj, wTq, wTp);
    qkv_kernel<<<dim3(16, BATCH * NH), 256, 0, stream>>>(x, wTq, b_qkv, Qb, Kb, Vtb);
    flash_kernel<<<dim3(16, NH, BATCH), 256, 0, stream>>>(Qb, Kb, Vtb, attn);
    proj_kernel<<<512, 256, 0, stream>>>(attn, wTp, b_proj, out);
}